// Round 5
// baseline (160.508 us; speedup 1.0000x reference)
//
#include <hip/hip_runtime.h>

#define NN 4
#define CC 20
#define HH 64
#define WW 2048
#define CG 4           // channel groups
#define CPG (CC / CG)  // 5 channels per group
#define PX 2           // pixels per thread (w)

// R3 inner structure (proven no-spill), PX=2 for 2x wave concurrency,
// 1D grid with (n,cg) fastest-varying => XCD-pinned channel groups.
__global__ __launch_bounds__(256, 4) void lc_xyz_kernel(
    const float* __restrict__ xyz,
    const float* __restrict__ softmax,
    const int* __restrict__ mask,
    float* __restrict__ out)
{
    // bid = ((h*4 + wb) << 4) | (n*4+cg)  -> bid%8 constant per (n,cg): XCD-pinned.
    const int bid = blockIdx.x;
    const int nz  = bid & 15;        // n*4+cg
    const int r   = bid >> 4;        // 0..255
    const int wb  = r & 3;           // w quarter
    const int h   = r >> 2;          // 0..63
    const int n   = nz >> 2;
    const int cg  = nz & 3;

    const int hw = HH * WW;
    const int t  = wb * 256 + threadIdx.x;   // pixel-pair index in row, 0..1023
    const int p0 = t * PX;

    const float* xb  = xyz     + (size_t)n * 3  * hw;
    const float* smb = softmax + (size_t)n * CC * hw + (size_t)(cg * CPG) * hw;
    const int*   mb  = mask    + (size_t)n * hw;

    const int ctr = h * WW + p0;
    const float2 cxv = *(const float2*)(xb + 0 * hw + ctr);
    const float2 cyv = *(const float2*)(xb + 1 * hw + ctr);
    const float2 czv = *(const float2*)(xb + 2 * hw + ctr);
    const float cx[PX] = {cxv.x, cxv.y};
    const float cy[PX] = {cyv.x, cyv.y};
    const float cz[PX] = {czv.x, czv.y};

    float acc[CPG][PX];
#pragma unroll
    for (int c = 0; c < CPG; ++c)
#pragma unroll
        for (int i = 0; i < PX; ++i) acc[c][i] = 0.f;

    // w-window: j=0..5 maps to w = p0-2+j; taps use j = i+dx in [0,5].
    // Aligned 8B chunks at p0-2, p0, p0+2; edge chunks clamped (invalid taps
    // zeroed via vf; all VALID taps come from unclamped chunks).
    int c0 = p0 - 2; if (c0 < 0) c0 = 0;
    const int c1 = p0;
    int c2 = p0 + 2; if (c2 > WW - 2) c2 = WW - 2;

    float vf[6];
#pragma unroll
    for (int j = 0; j < 6; ++j)
        vf[j] = ((unsigned)(p0 - 2 + j) < (unsigned)WW) ? 1.f : 0.f;

#pragma unroll
    for (int dy = -2; dy <= 2; ++dy) {
        const int row = h + dy;
        if ((unsigned)row >= (unsigned)HH) continue;   // block-uniform
        const int rb = row * WW;

        // Batched independent row loads: 3 int2 + 9 float2.
        const int2 m0 = *(const int2*)(mb + rb + c0);
        const int2 m1 = *(const int2*)(mb + rb + c1);
        const int2 m2 = *(const int2*)(mb + rb + c2);
        const float2 x0 = *(const float2*)(xb + 0 * hw + rb + c0);
        const float2 x1 = *(const float2*)(xb + 0 * hw + rb + c1);
        const float2 x2 = *(const float2*)(xb + 0 * hw + rb + c2);
        const float2 y0 = *(const float2*)(xb + 1 * hw + rb + c0);
        const float2 y1 = *(const float2*)(xb + 1 * hw + rb + c1);
        const float2 y2 = *(const float2*)(xb + 1 * hw + rb + c2);
        const float2 z0 = *(const float2*)(xb + 2 * hw + rb + c0);
        const float2 z1 = *(const float2*)(xb + 2 * hw + rb + c1);
        const float2 z2 = *(const float2*)(xb + 2 * hw + rb + c2);

        const float xw[6] = {x0.x,x0.y, x1.x,x1.y, x2.x,x2.y};
        const float yw[6] = {y0.x,y0.y, y1.x,y1.y, y2.x,y2.y};
        const float zw[6] = {z0.x,z0.y, z1.x,z1.y, z2.x,z2.y};
        const int   mi[6] = {m0.x,m0.y, m1.x,m1.y, m2.x,m2.y};

        float mf[6];
#pragma unroll
        for (int j = 0; j < 6; ++j) mf[j] = vf[j] * (float)mi[j];

        // Gaussian weights, once per (pixel, tap), shared across channels.
        float g[PX][5];
#pragma unroll
        for (int i = 0; i < PX; ++i) {
#pragma unroll
            for (int dx = 0; dx < 5; ++dx) {
                const int j = i + dx;
                const float ax = xw[j] - cx[i];
                const float ay = yw[j] - cy[i];
                const float az = zw[j] - cz[i];
                const float d2 = ax * ax + ay * ay + az * az;
                g[i][dx] = mf[j] * __expf(-0.5f * d2);
            }
        }

        // Channel loop: 3 float2 loads + 10 FMA per channel.
#pragma unroll
        for (int c = 0; c < CPG; ++c) {
            const float* sp = smb + (size_t)c * hw + rb;
            const float2 s0 = *(const float2*)(sp + c0);
            const float2 s1 = *(const float2*)(sp + c1);
            const float2 s2 = *(const float2*)(sp + c2);
            const float sw[6] = {s0.x,s0.y, s1.x,s1.y, s2.x,s2.y};
#pragma unroll
            for (int i = 0; i < PX; ++i) {
                float a = acc[c][i];
#pragma unroll
                for (int dx = 0; dx < 5; ++dx)
                    a = fmaf(g[i][dx], sw[i + dx], a);
                acc[c][i] = a;
            }
        }
    }

    float* ob = out + (size_t)n * CC * hw + (size_t)(cg * CPG) * hw + ctr;
#pragma unroll
    for (int c = 0; c < CPG; ++c)
        *(float2*)(ob + (size_t)c * hw) = make_float2(acc[c][0], acc[c][1]);
}

extern "C" void kernel_launch(void* const* d_in, const int* in_sizes, int n_in,
                              void* d_out, int out_size, void* d_ws, size_t ws_size,
                              hipStream_t stream) {
    const float* xyz     = (const float*)d_in[0];
    const float* softmax = (const float*)d_in[1];
    const int*   mask    = (const int*)d_in[2];
    float*       out     = (float*)d_out;

    dim3 block(256, 1, 1);
    // (W/(PX*256)) * HH * NN*CG = 4 * 64 * 16 = 4096 blocks, 1D swizzled.
    dim3 grid((WW / (PX * 256)) * HH * NN * CG, 1, 1);
    hipLaunchKernelGGL(lc_xyz_kernel, grid, block, 0, stream,
                       xyz, softmax, mask, out);
}

// Round 7
// 138.231 us; speedup vs baseline: 1.1612x; 1.1612x over previous
//
#include <hip/hip_runtime.h>

#define NN 4
#define CC 20
#define HH 64
#define WW 2048
#define CG 4           // channel groups
#define CPG (CC / CG)  // 5 channels per group
#define PX 4           // pixels per thread (w)

typedef float vfloat4 __attribute__((ext_vector_type(4)));  // native vec for NT store

// R3 compute structure (proven: VGPR 64, no spill) + 1D XCD-pinned swizzle
// ((n,cg) fastest-varying, 16 groups over 8 XCDs -> bid%8 constant per group,
// softmax slice stays in one XCD's L2) + non-temporal output stores.
__global__ __launch_bounds__(256, 3) void lc_xyz_kernel(
    const float* __restrict__ xyz,
    const float* __restrict__ softmax,
    const int* __restrict__ mask,
    float* __restrict__ out)
{
    const int bid = blockIdx.x;
    const int nz  = bid & 15;       // n*4+cg  (fastest-varying -> XCD-pinned)
    const int r   = bid >> 4;       // 0..127
    const int wb  = r & 1;          // w half
    const int h   = r >> 1;         // 0..63
    const int n   = nz >> 2;
    const int cg  = nz & 3;

    const int hw = HH * WW;
    const int t  = wb * 256 + threadIdx.x;   // pixel-quad index in row, 0..511
    const int p0 = t * PX;

    const float* xb  = xyz     + (size_t)n * 3  * hw;
    const float* smb = softmax + (size_t)n * CC * hw + (size_t)(cg * CPG) * hw;
    const int*   mb  = mask    + (size_t)n * hw;

    const int ctr = h * WW + p0;
    const float4 cxv = *(const float4*)(xb + 0 * hw + ctr);
    const float4 cyv = *(const float4*)(xb + 1 * hw + ctr);
    const float4 czv = *(const float4*)(xb + 2 * hw + ctr);
    const float cx[PX] = {cxv.x, cxv.y, cxv.z, cxv.w};
    const float cy[PX] = {cyv.x, cyv.y, cyv.z, cyv.w};
    const float cz[PX] = {czv.x, czv.y, czv.z, czv.w};

    float acc[CPG][PX];
#pragma unroll
    for (int c = 0; c < CPG; ++c)
#pragma unroll
        for (int i = 0; i < PX; ++i) acc[c][i] = 0.f;

    // w-window: j=0..11 maps to w = p0-4+j; taps use j = i+dx+2 in [2,9].
    // Aligned 16B chunks at p0-4, p0, p0+4; edge chunks clamped (invalid taps
    // zeroed via vf; all VALID taps come from unclamped chunks).
    int c0 = p0 - 4; if (c0 < 0) c0 = 0;
    const int c1 = p0;
    int c2 = p0 + 4; if (c2 > WW - 4) c2 = WW - 4;

    float vf[12];
#pragma unroll
    for (int j = 2; j <= 9; ++j)
        vf[j] = ((unsigned)(p0 - 4 + j) < (unsigned)WW) ? 1.f : 0.f;

#pragma unroll
    for (int dy = -2; dy <= 2; ++dy) {
        const int row = h + dy;
        if ((unsigned)row >= (unsigned)HH) continue;   // block-uniform
        const int rb = row * WW;

        // Batched independent row loads: 3 int4 + 9 float4.
        const int4 m0 = *(const int4*)(mb + rb + c0);
        const int4 m1 = *(const int4*)(mb + rb + c1);
        const int4 m2 = *(const int4*)(mb + rb + c2);
        const float4 x0 = *(const float4*)(xb + 0 * hw + rb + c0);
        const float4 x1 = *(const float4*)(xb + 0 * hw + rb + c1);
        const float4 x2 = *(const float4*)(xb + 0 * hw + rb + c2);
        const float4 y0 = *(const float4*)(xb + 1 * hw + rb + c0);
        const float4 y1 = *(const float4*)(xb + 1 * hw + rb + c1);
        const float4 y2 = *(const float4*)(xb + 1 * hw + rb + c2);
        const float4 z0 = *(const float4*)(xb + 2 * hw + rb + c0);
        const float4 z1 = *(const float4*)(xb + 2 * hw + rb + c1);
        const float4 z2 = *(const float4*)(xb + 2 * hw + rb + c2);

        const float xw[12] = {x0.x,x0.y,x0.z,x0.w, x1.x,x1.y,x1.z,x1.w, x2.x,x2.y,x2.z,x2.w};
        const float yw[12] = {y0.x,y0.y,y0.z,y0.w, y1.x,y1.y,y1.z,y1.w, y2.x,y2.y,y2.z,y2.w};
        const float zw[12] = {z0.x,z0.y,z0.z,z0.w, z1.x,z1.y,z1.z,z1.w, z2.x,z2.y,z2.z,z2.w};
        const int   mi[12] = {m0.x,m0.y,m0.z,m0.w, m1.x,m1.y,m1.z,m1.w, m2.x,m2.y,m2.z,m2.w};

        float mf[12];
#pragma unroll
        for (int j = 2; j <= 9; ++j) mf[j] = vf[j] * (float)mi[j];

        // Gaussian weights, once per (pixel, tap), shared across channels.
        float g[PX][5];
#pragma unroll
        for (int i = 0; i < PX; ++i) {
#pragma unroll
            for (int dx = 0; dx < 5; ++dx) {
                const int j = i + dx + 2;
                const float ax = xw[j] - cx[i];
                const float ay = yw[j] - cy[i];
                const float az = zw[j] - cz[i];
                const float d2 = ax * ax + ay * ay + az * az;
                g[i][dx] = mf[j] * __expf(-0.5f * d2);
            }
        }

        // Channel loop: 3 float4 loads + 20 FMA per channel.
#pragma unroll
        for (int c = 0; c < CPG; ++c) {
            const float* sp = smb + (size_t)c * hw + rb;
            const float4 s0 = *(const float4*)(sp + c0);
            const float4 s1 = *(const float4*)(sp + c1);
            const float4 s2 = *(const float4*)(sp + c2);
            const float sw[12] = {s0.x,s0.y,s0.z,s0.w, s1.x,s1.y,s1.z,s1.w, s2.x,s2.y,s2.z,s2.w};
#pragma unroll
            for (int i = 0; i < PX; ++i) {
                float a = acc[c][i];
#pragma unroll
                for (int dx = 0; dx < 5; ++dx)
                    a = fmaf(g[i][dx], sw[i + dx + 2], a);
                acc[c][i] = a;
            }
        }
    }

    // Non-temporal output stores: write-once data, keep it out of L2.
    float* ob = out + (size_t)n * CC * hw + (size_t)(cg * CPG) * hw + ctr;
#pragma unroll
    for (int c = 0; c < CPG; ++c) {
        vfloat4 v = {acc[c][0], acc[c][1], acc[c][2], acc[c][3]};
        __builtin_nontemporal_store(v, (vfloat4*)(ob + (size_t)c * hw));
    }
}

extern "C" void kernel_launch(void* const* d_in, const int* in_sizes, int n_in,
                              void* d_out, int out_size, void* d_ws, size_t ws_size,
                              hipStream_t stream) {
    const float* xyz     = (const float*)d_in[0];
    const float* softmax = (const float*)d_in[1];
    const int*   mask    = (const int*)d_in[2];
    float*       out     = (float*)d_out;

    dim3 block(256, 1, 1);
    // 2(wb) * 64(h) * 16(nz) = 2048 blocks, 1D, nz fastest-varying.
    dim3 grid(2 * HH * (NN * CG), 1, 1);
    hipLaunchKernelGGL(lc_xyz_kernel, grid, block, 0, stream,
                       xyz, softmax, mask, out);
}